// Round 11
// baseline (436.745 us; speedup 1.0000x reference)
//
#include <hip/hip_runtime.h>
#include <hip/hip_bf16.h>

#define N_NODES 100000
#define N_EDGES 3200000
#define DIM 256
#define BN_EPS 1e-5f
#define BROWS 256
#define NBUCK ((N_NODES + BROWS - 1) / BROWS)   // 391
#define BIN_BLOCKS 512
#define EPB (N_EDGES / BIN_BLOCKS)              // 6250 exact
#define RPW 4                                   // rows per wave in spmm
#define NPART 64                                // stat partial buffers
#define CAP 10240                               // bucket capacity (mean 8185, +22 sigma)
#define WFRAG_BLOCKS (DIM * DIM / 256)          // 256
#define GEMM_TILES (N_NODES / 32)               // 3125 exact (32 rows per wave)
#define GEMM_BLOCKS ((GEMM_TILES + 3) / 4)      // 782

typedef __attribute__((ext_vector_type(8))) short short8v;
typedef __attribute__((ext_vector_type(4))) float f32x4;

__device__ __forceinline__ float b2f(unsigned short h) {
    return __uint_as_float(((unsigned int)h) << 16);
}
__device__ __forceinline__ unsigned short f2b(float f) {
    unsigned int u = __float_as_uint(f);
    unsigned int rounded = u + 0x7FFF + ((u >> 16) & 1);
    return (unsigned short)(rounded >> 16);
}

// ============ Kernel A: bin (blocks 0..511)  ||  wfrag (blocks 512..767) ===
// The two tasks are fully independent; merging removes a dispatch and lets
// the small wfrag ride along free.
__global__ __launch_bounds__(256) void bin_wfrag_kernel(const int* __restrict__ rows,
                                                        const int* __restrict__ cols,
                                                        const float* __restrict__ vals,
                                                        int* bucketCnt,
                                                        int2* __restrict__ gBinned,
                                                        const float* __restrict__ W,
                                                        unsigned short* __restrict__ wfrag) {
    __shared__ int h[NBUCK];
    __shared__ int base[NBUCK];
    __shared__ int cur[NBUCK];
    const int t = threadIdx.x;

    if (blockIdx.x >= BIN_BLOCKS) {
        // ---- wfrag: W -> fragment-ready bf16 layout ----
        const int g = (blockIdx.x - BIN_BLOCKS) * 256 + t;
        const int e = g & 7;
        const int l = (g >> 3) & 63;
        const int frag = g >> 9;
        const int nt = frag >> 3;
        const int ks = frag & 7;
        const int k = ks * 32 + ((l >> 4) << 3) + e;
        const int c = nt * 16 + (l & 15);
        wfrag[g] = f2b(W[k * DIM + c]);
        return;
    }

    // ---- bin: fixed-capacity bucket scatter ----
    const int e0 = blockIdx.x * EPB;
    for (int i = t; i < NBUCK; i += 256) h[i] = 0;
    __syncthreads();
    for (int e = e0 + t; e < e0 + EPB; e += 256)
        atomicAdd(&h[rows[e] >> 8], 1);
    __syncthreads();
    for (int b = t; b < NBUCK; b += 256) {
        cur[b] = 0;
        if (h[b]) base[b] = atomicAdd(&bucketCnt[b], h[b]);
    }
    __syncthreads();
    for (int e = e0 + t; e < e0 + EPB; e += 256) {
        const int r = rows[e];
        const int b = r >> 8;
        const int rk = atomicAdd(&cur[b], 1);
        int2 p;
        p.x = ((r & 255) << 17) | cols[e];
        p.y = __float_as_int(vals[e]);
        gBinned[(size_t)b * CAP + base[b] + rk] = p;
    }
}

// ============ Kernel B: fine_sort (blocks 0..390) || gemm (391..) ==========
// R11 gemm change: 32 rows per wave (two A-fragment sets sharing each
// wfrag B-load). Per wave the 128KB wfrag stream now feeds 2x the MFMAs:
// L2 wfrag traffic 800 -> 400 MB total, load:MFMA ratio 1:2 with
// independent MFMA pairs pipelining back-to-back (the 16-deep serial
// nt-loop with 1:1 load:MFMA was the latency gate). 100000/32 = 3125 exact.
__global__ __launch_bounds__(256) void sort_gemm_kernel(const int* __restrict__ bucketCnt,
                                                        const int2* __restrict__ gBinned,
                                                        int* __restrict__ row_ptr,
                                                        int* __restrict__ row_end,
                                                        int2* __restrict__ finalE,
                                                        const float* __restrict__ x,
                                                        const unsigned short* __restrict__ wfrag,
                                                        unsigned short* __restrict__ zb) {
    __shared__ int h[BROWS];
    __shared__ int s[BROWS];
    __shared__ int cur[BROWS];
    const int t = threadIdx.x;

    if (blockIdx.x >= NBUCK) {
        // ---- gemm via MFMA: zb = bf16( x @ W ), 32 rows/wave ----
        const int wid = ((blockIdx.x - NBUCK) * 256 + t) >> 6;
        const int lane = t & 63;
        if (wid >= GEMM_TILES) return;
        const int m0 = wid * 32;

        const int kb = (lane >> 4) << 3;
        const float* xLo = x + (size_t)(m0 + (lane & 15)) * DIM + kb;
        const float* xHi = xLo + (size_t)16 * DIM;
        short8v afLo[8], afHi[8];
        #pragma unroll
        for (int ks = 0; ks < 8; ++ks) {
            float4 a0 = *(const float4*)(xLo + ks * 32);
            float4 a1 = *(const float4*)(xLo + ks * 32 + 4);
            short8v f;
            f[0] = (short)f2b(a0.x); f[1] = (short)f2b(a0.y);
            f[2] = (short)f2b(a0.z); f[3] = (short)f2b(a0.w);
            f[4] = (short)f2b(a1.x); f[5] = (short)f2b(a1.y);
            f[6] = (short)f2b(a1.z); f[7] = (short)f2b(a1.w);
            afLo[ks] = f;
            a0 = *(const float4*)(xHi + ks * 32);
            a1 = *(const float4*)(xHi + ks * 32 + 4);
            f[0] = (short)f2b(a0.x); f[1] = (short)f2b(a0.y);
            f[2] = (short)f2b(a0.z); f[3] = (short)f2b(a0.w);
            f[4] = (short)f2b(a1.x); f[5] = (short)f2b(a1.y);
            f[6] = (short)f2b(a1.z); f[7] = (short)f2b(a1.w);
            afHi[ks] = f;
        }

        const int r0 = (lane >> 4) << 2;
        const int dcol = lane & 15;
        for (int nt = 0; nt < 16; ++nt) {
            f32x4 accLo = {0.f, 0.f, 0.f, 0.f};
            f32x4 accHi = {0.f, 0.f, 0.f, 0.f};
            const unsigned short* wp = wfrag + ((size_t)(nt * 8) * 64 + lane) * 8;
            #pragma unroll
            for (int ks = 0; ks < 8; ++ks) {
                const short8v bf = *(const short8v*)(wp + (size_t)ks * 64 * 8);
                accLo = __builtin_amdgcn_mfma_f32_16x16x32_bf16(afLo[ks], bf, accLo, 0, 0, 0);
                accHi = __builtin_amdgcn_mfma_f32_16x16x32_bf16(afHi[ks], bf, accHi, 0, 0, 0);
            }
            unsigned short* zpLo = zb + (size_t)(m0 + r0) * DIM + nt * 16 + dcol;
            zpLo[0]       = f2b(accLo[0]);
            zpLo[DIM]     = f2b(accLo[1]);
            zpLo[2 * DIM] = f2b(accLo[2]);
            zpLo[3 * DIM] = f2b(accLo[3]);
            unsigned short* zpHi = zpLo + (size_t)16 * DIM;
            zpHi[0]       = f2b(accHi[0]);
            zpHi[DIM]     = f2b(accHi[1]);
            zpHi[2 * DIM] = f2b(accHi[2]);
            zpHi[3 * DIM] = f2b(accHi[3]);
        }
        return;
    }

    // ---- fine sort within bucket + row_ptr/row_end ----
    const int b = blockIdx.x;
    const int base0 = b * CAP;
    const int cnt = bucketCnt[b];
    h[t] = 0;
    __syncthreads();
    for (int e = base0 + t; e < base0 + cnt; e += 256)
        atomicAdd(&h[gBinned[e].x >> 17], 1);
    __syncthreads();
    s[t] = h[t];
    __syncthreads();
    for (int off = 1; off < BROWS; off <<= 1) {
        int x2 = (t >= off) ? s[t - off] : 0;
        __syncthreads();
        s[t] += x2;
        __syncthreads();
    }
    const int excl = s[t] - h[t];
    const int grow = b * BROWS + t;
    if (grow < N_NODES) {
        row_ptr[grow] = base0 + excl;
        row_end[grow] = base0 + s[t];
    }
    cur[t] = excl;
    __syncthreads();
    for (int e = base0 + t; e < base0 + cnt; e += 256) {
        const int2 p = gBinned[e];
        const int rl = p.x >> 17;
        const int rk = atomicAdd(&cur[rl], 1);
        int2 q;
        q.x = p.x & 0x1FFFF;
        q.y = p.y;
        finalE[base0 + rk] = q;
    }
}

// ---------------- SpMM (CSR gather) + fused BN stats ----------------------
// FROZEN at R6/R8 best structure (241 us): RPW=4 rows/wave, readfirstlane'd
// bounds, 8-deep double-batch pipeline, predicated tail, nt out store, LDS
// stats + NPART global-atomic partials. Seven structural variants (R0-R8)
// converge on ~3.8-3.9 TB/s at FETCH ~765 MB = the fabric/LLC gather floor.
__global__ __launch_bounds__(256) void spmm_csr_kernel(const int* __restrict__ row_ptr,
                                                       const int* __restrict__ row_end,
                                                       const int2* __restrict__ pairs,
                                                       const unsigned short* __restrict__ zb,
                                                       float* __restrict__ out,
                                                       float* __restrict__ partials) {
    __shared__ float sdata[2 * DIM];
    const int t = threadIdx.x;
    sdata[t] = 0.f;
    sdata[t + 256] = 0.f;
    __syncthreads();

    const int wave = (blockIdx.x * 256 + t) >> 6;
    const int lane = t & 63;
    const int row0 = wave * RPW;              // grid exact: 6250 blocks * 4 waves * 4 rows = 100000

    float4 s  = make_float4(0.f, 0.f, 0.f, 0.f);
    float4 sq = make_float4(0.f, 0.f, 0.f, 0.f);

    for (int row = row0; row < row0 + RPW; ++row) {
        const int start = __builtin_amdgcn_readfirstlane(row_ptr[row]);
        const int end   = __builtin_amdgcn_readfirstlane(row_end[row]);
        float4 acc = make_float4(0.f, 0.f, 0.f, 0.f);
        int2 pA[8], pB[8];
        ushort4 mA[8], mB[8];

#define LOADX(P, M, EB) do { \
    _Pragma("unroll") for (int j = 0; j < 8; ++j) P[j] = pairs[(EB) + j]; \
    _Pragma("unroll") for (int j = 0; j < 8; ++j) \
        M[j] = ((const ushort4*)(zb + (size_t)P[j].x * DIM))[lane]; \
  } while (0)
#define FMAX(P, M) do { \
    _Pragma("unroll") for (int j = 0; j < 8; ++j) { \
        const float v = __int_as_float(P[j].y); \
        acc.x += v * b2f(M[j].x); \
        acc.y += v * b2f(M[j].y); \
        acc.z += v * b2f(M[j].z); \
        acc.w += v * b2f(M[j].w); \
    } \
  } while (0)

        const int nb = (end - start) >> 3;
        int e = start;
        if (nb) {
            LOADX(pA, mA, e); e += 8;
            int b = 1;
            for (; b + 1 < nb; b += 2) {
                LOADX(pB, mB, e); e += 8;   // B in flight while A is consumed
                FMAX(pA, mA);
                LOADX(pA, mA, e); e += 8;   // A in flight while B is consumed
                FMAX(pB, mB);
            }
            if (b < nb) {
                LOADX(pB, mB, e); e += 8;
                FMAX(pA, mA);
                FMAX(pB, mB);
            } else {
                FMAX(pA, mA);
            }
        }
        // predicated tail batch (0..7 edges), uniform branches
        const int rem = end - e;
        if (rem) {
            #pragma unroll
            for (int j = 0; j < 8; ++j) if (j < rem) pA[j] = pairs[e + j];
            #pragma unroll
            for (int j = 0; j < 8; ++j) if (j < rem)
                mA[j] = ((const ushort4*)(zb + (size_t)pA[j].x * DIM))[lane];
            #pragma unroll
            for (int j = 0; j < 8; ++j) if (j < rem) {
                const float v = __int_as_float(pA[j].y);
                acc.x += v * b2f(mA[j].x);
                acc.y += v * b2f(mA[j].y);
                acc.z += v * b2f(mA[j].z);
                acc.w += v * b2f(mA[j].w);
            }
        }
#undef LOADX
#undef FMAX

        // nontemporal (no-allocate) out store
        f32x4 st = {acc.x, acc.y, acc.z, acc.w};
        __builtin_nontemporal_store(st, (f32x4*)(out + (size_t)row * DIM) + lane);

        s.x += acc.x; s.y += acc.y; s.z += acc.z; s.w += acc.w;
        sq.x += acc.x * acc.x; sq.y += acc.y * acc.y;
        sq.z += acc.z * acc.z; sq.w += acc.w * acc.w;
    }

    const int c0 = lane * 4;
    atomicAdd(&sdata[c0 + 0], s.x);
    atomicAdd(&sdata[c0 + 1], s.y);
    atomicAdd(&sdata[c0 + 2], s.z);
    atomicAdd(&sdata[c0 + 3], s.w);
    atomicAdd(&sdata[256 + c0 + 0], sq.x);
    atomicAdd(&sdata[256 + c0 + 1], sq.y);
    atomicAdd(&sdata[256 + c0 + 2], sq.z);
    atomicAdd(&sdata[256 + c0 + 3], sq.w);
    __syncthreads();

    float* pb = partials + (size_t)(blockIdx.x & (NPART - 1)) * (2 * DIM);
    atomicAdd(&pb[t], sdata[t]);
    atomicAdd(&pb[t + 256], sdata[t + 256]);
}

// ---------------- finalize: reduce partials, scale/bias per column --------
__global__ __launch_bounds__(256) void finalize_kernel(const float* __restrict__ partials,
                                                       const float* __restrict__ gamma,
                                                       const float* __restrict__ beta,
                                                       float* __restrict__ sb) {
    const int c = threadIdx.x;
    float s = 0.f, ssq = 0.f;
    for (int b = 0; b < NPART; ++b) {
        s   += partials[b * (2 * DIM) + c];
        ssq += partials[b * (2 * DIM) + 256 + c];
    }
    const float inv_n = 1.0f / (float)N_NODES;
    const float mean = s * inv_n;
    float var = ssq * inv_n - mean * mean;
    const float rstd = rsqrtf(var + BN_EPS);
    const float scale = rstd * gamma[c];
    sb[c] = scale;
    sb[DIM + c] = beta[c] - mean * scale;
}

// ---------------- normalize + ReLU (in-place on d_out) --------------------
#define NORM_BLOCKS 2048
__global__ __launch_bounds__(256) void norm_kernel(float* __restrict__ out,
                                                   const float* __restrict__ sb) {
    // compile-time stride (multiple of 64) => (idx & 63) == (threadIdx.x & 63)
    // for every iteration => scale/bias hoist to registers.
    const int c0 = (threadIdx.x & 63) * 4;
    const float s0 = sb[c0 + 0], s1 = sb[c0 + 1], s2 = sb[c0 + 2], s3 = sb[c0 + 3];
    const float b0 = sb[DIM + c0 + 0], b1 = sb[DIM + c0 + 1];
    const float b2 = sb[DIM + c0 + 2], b3 = sb[DIM + c0 + 3];
    const int nvec = N_NODES * (DIM / 4);
    for (int idx = blockIdx.x * 256 + threadIdx.x; idx < nvec; idx += NORM_BLOCKS * 256) {
        float4 a = ((float4*)out)[idx];
        float4 o;
        o.x = fmaxf(fmaf(a.x, s0, b0), 0.f);
        o.y = fmaxf(fmaf(a.y, s1, b1), 0.f);
        o.z = fmaxf(fmaf(a.z, s2, b2), 0.f);
        o.w = fmaxf(fmaf(a.w, s3, b3), 0.f);
        ((float4*)out)[idx] = o;
    }
}

extern "C" void kernel_launch(void* const* d_in, const int* in_sizes, int n_in,
                              void* d_out, int out_size, void* d_ws, size_t ws_size,
                              hipStream_t stream) {
    const float* x         = (const float*)d_in[0];
    const int*   edge_rows = (const int*)d_in[1];
    const int*   edge_cols = (const int*)d_in[2];
    const float* edge_vals = (const float*)d_in[3];
    const float* weight    = (const float*)d_in[4];
    const float* gamma     = (const float*)d_in[5];
    const float* beta      = (const float*)d_in[6];
    float* out = (float*)d_out;

    // workspace layout (~116 MB). gBinned has its own region (it is read by
    // fine_sort concurrently with gemm writing zb in kernel B).
    unsigned short* zb    = (unsigned short*)d_ws;             // 51.2 MB
    unsigned short* wfrag = zb + (size_t)N_NODES * DIM;        // 128 KB
    int2*  gBinned  = (int2*)(wfrag + DIM * DIM);              // 32 MB (own region)
    int2*  finalE   = gBinned + (size_t)NBUCK * CAP;           // 32 MB
    int*   row_ptr  = (int*)(finalE + (size_t)NBUCK * CAP);    // N ints
    int*   row_end  = row_ptr + N_NODES;                       // N ints
    int*   bucketCnt = row_end + N_NODES;                      // 391
    float* partials = (float*)(bucketCnt + NBUCK);             // 64*512 f32 = 128 KB
    float* sb       = partials + NPART * 2 * DIM;              // 512 f32

    // zero bucket cursors + stat partials (contiguous)
    hipMemsetAsync(bucketCnt, 0, (NBUCK + NPART * 2 * DIM) * sizeof(int), stream);

    // Kernel A: bin (512 blocks) || wfrag (256 blocks) — independent tasks
    bin_wfrag_kernel<<<BIN_BLOCKS + WFRAG_BLOCKS, 256, 0, stream>>>(
        edge_rows, edge_cols, edge_vals, bucketCnt, gBinned, weight, wfrag);

    // Kernel B: fine_sort (391 blocks) || gemm (782 blocks, 32 rows/wave)
    sort_gemm_kernel<<<NBUCK + GEMM_BLOCKS, 256, 0, stream>>>(
        bucketCnt, gBinned, row_ptr, row_end, finalE, x, wfrag, zb);

    // spmm + fused BN stats: 6250 blocks * 4 waves * 4 rows = 100000 rows exact
    spmm_csr_kernel<<<N_NODES / (RPW * 4), 256, 0, stream>>>(row_ptr, row_end, finalE, zb, out, partials);

    finalize_kernel<<<1, 256, 0, stream>>>(partials, gamma, beta, sb);
    norm_kernel<<<NORM_BLOCKS, 256, 0, stream>>>(out, sb);
}